// Round 2
// baseline (610.725 us; speedup 1.0000x reference)
//
#include <hip/hip_runtime.h>
#include <hip/hip_bf16.h>

#define GAS __attribute__((address_space(1)))
#define LAS __attribute__((address_space(3)))

typedef __bf16 bf16x8 __attribute__((ext_vector_type(8)));
typedef float f32x16 __attribute__((ext_vector_type(16)));

constexpr int Kd = 4096;   // IN
constexpr int Nd = 4096;   // OUT
constexpr int RANKd = 32;
constexpr int NG = 32;     // scale groups
constexpr int BM = 128, BN = 128, BK = 64;

// ---------------------------------------------------------------------------
// prep: fused W-build + x fp32->bf16 convert (unchanged).
// ---------------------------------------------------------------------------
constexpr int BWR = 32, BWC = 256;
constexpr int NBUILD = (Nd / BWR) * (Kd / BWC);   // 2048

__global__ __launch_bounds__(256) void prep(
    const int* __restrict__ q, const float* __restrict__ scales,
    const float* __restrict__ U, const float* __restrict__ V,
    __hip_bfloat16* __restrict__ W,
    const float* __restrict__ x, __hip_bfloat16* __restrict__ xb)
{
  __shared__ float V_s[RANKd][BWC + 4];
  __shared__ float U_s[BWR][RANKd + 1];

  const int t = threadIdx.x;
  const int bid = blockIdx.x;

  if (bid >= NBUILD) {   // ---- convert branch ----
    const size_t base = (size_t)(bid - NBUILD) * 8192;
    #pragma unroll
    for (int i = 0; i < 4; ++i) {
      const size_t idx = base + i * 2048 + t * 8;
      float4 a = *(const float4*)(x + idx);
      float4 b = *(const float4*)(x + idx + 4);
      union { __hip_bfloat16 h[8]; int4 v; } u;
      u.h[0] = __float2bfloat16(a.x); u.h[1] = __float2bfloat16(a.y);
      u.h[2] = __float2bfloat16(a.z); u.h[3] = __float2bfloat16(a.w);
      u.h[4] = __float2bfloat16(b.x); u.h[5] = __float2bfloat16(b.y);
      u.h[6] = __float2bfloat16(b.z); u.h[7] = __float2bfloat16(b.w);
      *(int4*)(xb + idx) = u.v;
    }
    return;
  }

  // ---- build branch ----
  const int bx = bid & 15;
  const int by = bid >> 4;
  const int n0 = by * BWR;
  const int k0 = bx * BWC;

  {  // stage U: 32x32 floats
    const int idx = t * 4;
    const int row = idx >> 5, rr = idx & 31;
    float4 uv = *(const float4*)(U + (size_t)(n0 + row) * RANKd + rr);
    U_s[row][rr] = uv.x; U_s[row][rr + 1] = uv.y;
    U_s[row][rr + 2] = uv.z; U_s[row][rr + 3] = uv.w;
  }
  #pragma unroll
  for (int i = 0; i < 8; ++i) {  // stage V: 32x256 floats
    const int idx = i * 1024 + t * 4;
    const int vr = idx >> 8, vc = idx & 255;
    *(float4*)&V_s[vr][vc] = *(const float4*)(V + (size_t)vr * Kd + k0 + vc);
  }
  __syncthreads();

  const int rs = t >> 5;
  const int cs = t & 31;
  const int row0 = n0 + rs * 4;
  const int c0 = cs * 4;
  const int c1 = 128 + cs * 4;
  const int g0 = k0 >> 7, g1 = g0 + 1;

  float acc[4][8];
  #pragma unroll
  for (int j = 0; j < 4; ++j) {
    const int* qr = q + (size_t)(row0 + j) * Kd + k0;
    int4 a = *(const int4*)(qr + c0);
    int4 b = *(const int4*)(qr + c1);
    const float s0 = scales[(size_t)(row0 + j) * NG + g0];
    const float s1 = scales[(size_t)(row0 + j) * NG + g1];
    acc[j][0] = (float)(a.x - 8) * s0; acc[j][1] = (float)(a.y - 8) * s0;
    acc[j][2] = (float)(a.z - 8) * s0; acc[j][3] = (float)(a.w - 8) * s0;
    acc[j][4] = (float)(b.x - 8) * s1; acc[j][5] = (float)(b.y - 8) * s1;
    acc[j][6] = (float)(b.z - 8) * s1; acc[j][7] = (float)(b.w - 8) * s1;
  }

  #pragma unroll 4
  for (int r = 0; r < RANKd; ++r) {
    float4 v0 = *(const float4*)&V_s[r][c0];
    float4 v1 = *(const float4*)&V_s[r][c1];
    #pragma unroll
    for (int j = 0; j < 4; ++j) {
      const float u = U_s[rs * 4 + j][r];
      acc[j][0] += u * v0.x; acc[j][1] += u * v0.y;
      acc[j][2] += u * v0.z; acc[j][3] += u * v0.w;
      acc[j][4] += u * v1.x; acc[j][5] += u * v1.y;
      acc[j][6] += u * v1.z; acc[j][7] += u * v1.w;
    }
  }

  #pragma unroll
  for (int j = 0; j < 4; ++j) {
    union { __hip_bfloat16 h[4]; uint2 v; } o0, o1;
    o0.h[0] = __float2bfloat16(acc[j][0]); o0.h[1] = __float2bfloat16(acc[j][1]);
    o0.h[2] = __float2bfloat16(acc[j][2]); o0.h[3] = __float2bfloat16(acc[j][3]);
    o1.h[0] = __float2bfloat16(acc[j][4]); o1.h[1] = __float2bfloat16(acc[j][5]);
    o1.h[2] = __float2bfloat16(acc[j][6]); o1.h[3] = __float2bfloat16(acc[j][7]);
    __hip_bfloat16* wr = W + (size_t)(row0 + j) * Kd + k0;
    *(uint2*)(wr + c0) = o0.v;
    *(uint2*)(wr + c1) = o1.v;
  }
}

// ---------------------------------------------------------------------------
// gemm256: 256x256 tile, BK=64 staged as 2 K-halves of 32, 8 waves (512 thr),
// 2Mx4N wave grid, 4x2 32x32x16 MFMA frags/wave.
//
// ROUND 2 CHANGE: 2-slot LDS pipeline (64 KB total -> 2 blocks/CU, was 1).
// Per-CU LDS demand per phase (96 KB read + 96 KB DMA write ~ 1536 cyc)
// exceeds MFMA demand (1033 cyc); with 1 block/CU they serialize (measured
// 2810 cyc/block-phase). Two co-resident unsynced blocks let one block's
// MFMA overlap the other's LDS window.
//
// Phase g: vmcnt(4) [own slot-g loads landed] -> barrier -> ds_read slot g&1
// -> lgkmcnt(0) -> barrier [all waves done reading] -> ISSUE g+2 into the
// just-read slot -> 16 MFMA. Counted vmcnt keeps 8 loads (2 phases ~2600 cyc
// >> 900 cyc HBM latency) in flight; never drains to 0 in steady state.
// Chunk-XOR swizzle geometry unchanged (proven conflict-free): slot
// addr(r,c) = r*64 + ((c ^ ((r>>1)&3))*16); staging pre-swizzles the GLOBAL
// source chunk so global_load_lds dest stays linear (both-sides rule).
// ---------------------------------------------------------------------------
#define WAIT_VM4 asm volatile("s_waitcnt vmcnt(4)" ::: "memory")
#define WAIT_VM0 asm volatile("s_waitcnt vmcnt(0)" ::: "memory")

// issue one K-half (A: 2 insts, B: 2 insts) into slot (G)&1
#define ISSUE4(G)                                                               \
  {                                                                             \
    const int so_ = ((G) & 1) * 16384;                                          \
    const size_t ko_ = (size_t)(G) * 32;                                        \
    __builtin_amdgcn_global_load_lds((GAS void*)(ag0 + ko_),                    \
        (LAS void*)(smc + so_ + ldsA), 16, 0, 0);                               \
    __builtin_amdgcn_global_load_lds((GAS void*)(ag1 + ko_),                    \
        (LAS void*)(smc + so_ + ldsA + 1024), 16, 0, 0);                        \
    __builtin_amdgcn_global_load_lds((GAS void*)(bg0 + ko_),                    \
        (LAS void*)(smc + so_ + ldsB), 16, 0, 0);                               \
    __builtin_amdgcn_global_load_lds((GAS void*)(bg1 + ko_),                    \
        (LAS void*)(smc + so_ + ldsB + 1024), 16, 0, 0);                        \
  }

// one phase of the 2-slot pipeline (see header comment for hazard analysis)
#define GPHASE(G, WAITSTMT, DO_ISSUE)                                           \
  {                                                                             \
    WAITSTMT;                                                                   \
    __builtin_amdgcn_s_barrier();                                               \
    __builtin_amdgcn_sched_barrier(0);                                          \
    const char* as_ = (const char*)smc + ((G) & 1) * 16384;                     \
    bf16x8 af0[4], af1[4], bfA[2], bfB[2];                                      \
    _Pragma("unroll")                                                           \
    for (int mi = 0; mi < 4; ++mi) {                                            \
      af0[mi] = *(const bf16x8*)(as_ + aro + mi * 2048 + cq0);                  \
      af1[mi] = *(const bf16x8*)(as_ + aro + mi * 2048 + cq1);                  \
    }                                                                           \
    _Pragma("unroll")                                                           \
    for (int nj = 0; nj < 2; ++nj) {                                            \
      bfA[nj] = *(const bf16x8*)(as_ + bro + nj * 2048 + cq0);                  \
      bfB[nj] = *(const bf16x8*)(as_ + bro + nj * 2048 + cq1);                  \
    }                                                                           \
    asm volatile("s_waitcnt lgkmcnt(0)" ::: "memory");                          \
    __builtin_amdgcn_sched_barrier(0);                                          \
    __builtin_amdgcn_s_barrier();                                               \
    __builtin_amdgcn_sched_barrier(0);                                          \
    if (DO_ISSUE) { ISSUE4((G) + 2); }                                          \
    __builtin_amdgcn_sched_barrier(0);                                          \
    __builtin_amdgcn_s_setprio(1);                                              \
    _Pragma("unroll")                                                           \
    for (int mi = 0; mi < 4; ++mi)                                              \
      _Pragma("unroll")                                                         \
      for (int nj = 0; nj < 2; ++nj)                                            \
        acc[mi][nj] = __builtin_amdgcn_mfma_f32_32x32x16_bf16(                  \
            af0[mi], bfA[nj], acc[mi][nj], 0, 0, 0);                            \
    _Pragma("unroll")                                                           \
    for (int mi = 0; mi < 4; ++mi)                                              \
      _Pragma("unroll")                                                         \
      for (int nj = 0; nj < 2; ++nj)                                            \
        acc[mi][nj] = __builtin_amdgcn_mfma_f32_32x32x16_bf16(                  \
            af1[mi], bfB[nj], acc[mi][nj], 0, 0, 0);                            \
    __builtin_amdgcn_s_setprio(0);                                              \
  }

__global__ __launch_bounds__(512, 2) void gemm256(
    const __hip_bfloat16* __restrict__ A, const __hip_bfloat16* __restrict__ Bt,
    const float* __restrict__ bias, float* __restrict__ C)
{
  // A slots: [0,32K) (2 x 16 KB), B slots: [32K,64K) (2 x 16 KB).
  __shared__ __align__(16) char sm[65536];
  char* const smc = sm;

  int bx, by;
  {
    const int bid = blockIdx.x;
    if (gridDim.x == 512) {            // bijective XCD-aware swizzle (8 XCDs)
      const int x = bid & 7, loc = bid >> 3;       // 64 blocks per XCD
      by = (x >> 2) * 16 + (loc & 15);             // 2 xcd-rows x 16
      bx = (x & 3) * 4 + (loc >> 4);               // 4 xcd-cols x 4
    } else {
      bx = bid % (Nd / 256);
      by = bid / (Nd / 256);
    }
  }
  const int bm0 = by * 256, bn0 = bx * 256;

  const int t = threadIdx.x;
  const int l = t & 63, w = t >> 6;

  // ---- staging addressing (wave w stages rows [w*32, w*32+32) of A and B)
  const int sr   = l >> 2;
  const int schk = (l & 3) ^ ((l >> 3) & 3);       // pre-swizzled global chunk
  const __hip_bfloat16* ag0 = A  + (size_t)(bm0 + w * 32 + sr) * Kd + schk * 8;
  const __hip_bfloat16* ag1 = ag0 + (size_t)16 * Kd;
  const __hip_bfloat16* bg0 = Bt + (size_t)(bn0 + w * 32 + sr) * Kd + schk * 8;
  const __hip_bfloat16* bg1 = bg0 + (size_t)16 * Kd;
  const int ldsA = w * 2048 + l * 16;
  const int ldsB = 32768 + ldsA;

  // ---- fragment addressing (wave (wm,wn) owns a 128x64 output block)
  const int wm = w >> 2, wn = w & 3;
  const int rl = l & 31, kh = l >> 5, swz = (rl >> 1) & 3;
  const int aro = (wm * 128 + rl) * 64;
  const int bro = 32768 + (wn * 64 + rl) * 64;
  const int cq0 = (kh ^ swz) * 16;                 // ks=0 chunk slot
  const int cq1 = ((2 + kh) ^ swz) * 16;           // ks=1 chunk slot

  f32x16 acc[4][2];
  #pragma unroll
  for (int mi = 0; mi < 4; ++mi)
    #pragma unroll
    for (int nj = 0; nj < 2; ++nj)
      acc[mi][nj] = (f32x16)(0.f);

  // ---- prologue: fill both slots (halves 0 and 1)
  ISSUE4(0);
  ISSUE4(1);

  // ---- 128 phases (one per K-half). Steady state: 2 halves (8 loads) in
  // flight. Phases 0..125 issue half g+2; 126/127 drain.
  #pragma unroll 2
  for (int g = 0; g < 126; ++g) {
    GPHASE(g, WAIT_VM4, 1);
  }
  GPHASE(126, WAIT_VM4, 0);
  GPHASE(127, WAIT_VM0, 0);

  // ---- epilogue: C/D layout col=lane&31, row=(reg&3)+8*(reg>>2)+4*(lane>>5)
  #pragma unroll
  for (int nj = 0; nj < 2; ++nj) {
    const int col = bn0 + wn * 64 + nj * 32 + rl;
    const float bz = bias[col];
    #pragma unroll
    for (int mi = 0; mi < 4; ++mi) {
      const int rbase = bm0 + wm * 128 + mi * 32 + 4 * kh;
      #pragma unroll
      for (int reg = 0; reg < 16; ++reg) {
        const int row = rbase + (reg & 3) + 8 * (reg >> 2);
        C[(size_t)row * Nd + col] = acc[mi][nj][reg] + bz;
      }
    }
  }
}

#undef GPHASE
#undef ISSUE4

// ---------------------------------------------------------------------------
// gemm_bt: old 128x128 kernel, kept only as the small-workspace fallback
// (fp32-A path).
// ---------------------------------------------------------------------------
template <bool ABF16>
__global__ __launch_bounds__(256) void gemm_bt(
    const void* __restrict__ Ap, const __hip_bfloat16* __restrict__ Bt,
    const float* __restrict__ bias, float* __restrict__ C)
{
  __shared__ __hip_bfloat16 As[BM * BK];   // 16 KB = 2 slabs x 8 KB
  __shared__ __hip_bfloat16 Bs[BN * BK];   // 16 KB

  const int t  = threadIdx.x;
  const int l  = t & 63;
  const int w  = t >> 6;
  const int wm = w >> 1;
  const int wn = w & 1;
  const int bm0 = blockIdx.y * BM;
  const int bn0 = blockIdx.x * BN;

  f32x16 acc[2][2];
  #pragma unroll
  for (int i = 0; i < 2; ++i)
    #pragma unroll
    for (int j = 0; j < 2; ++j)
      acc[i][j] = (f32x16)(0.f);

  const __hip_bfloat16* Abf = (const __hip_bfloat16*)Ap;
  const float*          A32 = (const float*)Ap;

  const int sr   = l >> 2;
  const int schk = (l & 3) ^ ((l >> 3) & 3);
  const __hip_bfloat16* ag0 = Abf + (size_t)(bm0 + w * 32 + sr) * Kd + schk * 8;
  const __hip_bfloat16* bg0 = Bt  + (size_t)(bn0 + w * 32 + sr) * Kd + schk * 8;
  char* asb = (char*)As + w * 2048;
  char* bsb = (char*)Bs + w * 2048;

  const int rl = l & 31, kh = l >> 5, swz = (rl >> 1) & 3;
  const char* Ard = (const char*)As + (wm * 64 + rl) * 64;
  const char* Brd = (const char*)Bs + (wn * 64 + rl) * 64;

  const int arow = t >> 1, aslab = t & 1, arx = (arow >> 1) & 3;
  const float* a32p = A32 + (size_t)(bm0 + arow) * Kd + aslab * 32;
  char* awr = (char*)As + aslab * 8192 + arow * 64;

  for (int kt = 0; kt < Kd / BK; ++kt) {
    if constexpr (ABF16) {
      const __hip_bfloat16* ag = ag0 + kt * BK;
      __builtin_amdgcn_global_load_lds((GAS void*)ag,               (LAS void*)asb,                16, 0, 0);
      __builtin_amdgcn_global_load_lds((GAS void*)(ag + 16 * Kd),   (LAS void*)(asb + 1024),       16, 0, 0);
      __builtin_amdgcn_global_load_lds((GAS void*)(ag + 32),        (LAS void*)(asb + 8192),       16, 0, 0);
      __builtin_amdgcn_global_load_lds((GAS void*)(ag + 16*Kd + 32),(LAS void*)(asb + 8192 + 1024),16, 0, 0);
    } else {
      const float* ap = a32p + kt * BK;
      #pragma unroll
      for (int cc = 0; cc < 4; ++cc) {
        float4 f0 = ((const float4*)ap)[cc * 2];
        float4 f1 = ((const float4*)ap)[cc * 2 + 1];
        union { __hip_bfloat16 h[8]; int4 v; } u;
        u.h[0] = __float2bfloat16(f0.x); u.h[1] = __float2bfloat16(f0.y);
        u.h[2] = __float2bfloat16(f0.z); u.h[3] = __float2bfloat16(f0.w);
        u.h[4] = __float2bfloat16(f1.x); u.h[5] = __float2bfloat16(f1.y);
        u.h[6] = __float2bfloat16(f1.z); u.h[7] = __float2bfloat16(f1.w);
        *(int4*)(awr + ((cc ^ arx) * 16)) = u.v;
      }
    }
    {
      const __hip_bfloat16* bg = bg0 + kt * BK;
      __builtin_amdgcn_global_load_lds((GAS void*)bg,               (LAS void*)bsb,                16, 0, 0);
      __builtin_amdgcn_global_load_lds((GAS void*)(bg + 16 * Kd),   (LAS void*)(bsb + 1024),       16, 0, 0);
      __builtin_amdgcn_global_load_lds((GAS void*)(bg + 32),        (LAS void*)(bsb + 8192),       16, 0, 0);
      __builtin_amdgcn_global_load_lds((GAS void*)(bg + 16*Kd + 32),(LAS void*)(bsb + 8192 + 1024),16, 0, 0);
    }

    __syncthreads();

    bf16x8 af[2][4], bfr[2][4];
    #pragma unroll
    for (int mi = 0; mi < 2; ++mi)
      #pragma unroll
      for (int ks = 0; ks < 4; ++ks)
        af[mi][ks] = *(const bf16x8*)(Ard + (ks >> 1) * 8192 + mi * 2048 +
                                      ((((ks & 1) * 2 + kh) ^ swz) * 16));
    #pragma unroll
    for (int nj = 0; nj < 2; ++nj)
      #pragma unroll
      for (int ks = 0; ks < 4; ++ks)
        bfr[nj][ks] = *(const bf16x8*)(Brd + (ks >> 1) * 8192 + nj * 2048 +
                                       ((((ks & 1) * 2 + kh) ^ swz) * 16));

    #pragma unroll
    for (int ks = 0; ks < 4; ++ks)
      #pragma unroll
      for (int mi = 0; mi < 2; ++mi)
        #pragma unroll
        for (int nj = 0; nj < 2; ++nj)
          acc[mi][nj] = __builtin_amdgcn_mfma_f32_32x32x16_bf16(
              af[mi][ks], bfr[nj][ks], acc[mi][nj], 0, 0, 0);

    __syncthreads();
  }

  #pragma unroll
  for (int nj = 0; nj < 2; ++nj) {
    const int col = bn0 + wn * 64 + nj * 32 + rl;
    const float bz = bias[col];
    #pragma unroll
    for (int mi = 0; mi < 2; ++mi) {
      const int rbase = bm0 + wm * 64 + mi * 32 + 4 * kh;
      #pragma unroll
      for (int reg = 0; reg < 16; ++reg) {
        const int row = rbase + (reg & 3) + 8 * (reg >> 2);
        C[(size_t)row * Nd + col] = acc[mi][nj][reg] + bz;
      }
    }
  }
}

// ---------------------------------------------------------------------------
extern "C" void kernel_launch(void* const* d_in, const int* in_sizes, int n_in,
                              void* d_out, int out_size, void* d_ws, size_t ws_size,
                              hipStream_t stream)
{
  const float* x      = (const float*)d_in[0];
  const int*   q      = (const int*)  d_in[1];
  const float* scales = (const float*)d_in[2];
  const float* U      = (const float*)d_in[3];
  const float* V      = (const float*)d_in[4];
  const float* bias   = (const float*)d_in[5];
  float* out = (float*)d_out;

  const int M = in_sizes[0] / Kd;   // B*S = 8192

  __hip_bfloat16* Wb = (__hip_bfloat16*)d_ws;
  const size_t wbytes = (size_t)Nd * Kd * sizeof(__hip_bfloat16);
  const size_t xbytes = (size_t)M  * Kd * sizeof(__hip_bfloat16);

  if (ws_size >= wbytes + xbytes && (M % 256) == 0) {
    __hip_bfloat16* Xb = (__hip_bfloat16*)((char*)d_ws + wbytes);
    const int nconv = (int)(((size_t)M * Kd) / 8192);
    prep<<<dim3(NBUILD + nconv), dim3(256), 0, stream>>>(q, scales, U, V, Wb, x, Xb);
    const int nblk = (M / 256) * (Nd / 256);
    gemm256<<<dim3(nblk), dim3(512), 0, stream>>>(Xb, Wb, bias, out);
  } else {
    prep<<<dim3(NBUILD), dim3(256), 0, stream>>>(q, scales, U, V, Wb, x, nullptr);
    dim3 grid(Nd / BN, M / BM);
    gemm_bt<false><<<grid, dim3(256), 0, stream>>>((const void*)x, Wb, bias, out);
  }
}

// Round 4
// 551.912 us; speedup vs baseline: 1.1066x; 1.1066x over previous
//
#include <hip/hip_runtime.h>
#include <hip/hip_bf16.h>

#define GAS __attribute__((address_space(1)))
#define LAS __attribute__((address_space(3)))

typedef __bf16 bf16x8 __attribute__((ext_vector_type(8)));
typedef float f32x16 __attribute__((ext_vector_type(16)));

constexpr int Kd = 4096;   // IN
constexpr int Nd = 4096;   // OUT
constexpr int RANKd = 32;
constexpr int NG = 32;     // scale groups
constexpr int BM = 128, BN = 128, BK = 64;

// ---------------------------------------------------------------------------
// prep: fused W-build + x fp32->bf16 convert (unchanged).
// ---------------------------------------------------------------------------
constexpr int BWR = 32, BWC = 256;
constexpr int NBUILD = (Nd / BWR) * (Kd / BWC);   // 2048

__global__ __launch_bounds__(256) void prep(
    const int* __restrict__ q, const float* __restrict__ scales,
    const float* __restrict__ U, const float* __restrict__ V,
    __hip_bfloat16* __restrict__ W,
    const float* __restrict__ x, __hip_bfloat16* __restrict__ xb)
{
  __shared__ float V_s[RANKd][BWC + 4];
  __shared__ float U_s[BWR][RANKd + 1];

  const int t = threadIdx.x;
  const int bid = blockIdx.x;

  if (bid >= NBUILD) {   // ---- convert branch ----
    const size_t base = (size_t)(bid - NBUILD) * 8192;
    #pragma unroll
    for (int i = 0; i < 4; ++i) {
      const size_t idx = base + i * 2048 + t * 8;
      float4 a = *(const float4*)(x + idx);
      float4 b = *(const float4*)(x + idx + 4);
      union { __hip_bfloat16 h[8]; int4 v; } u;
      u.h[0] = __float2bfloat16(a.x); u.h[1] = __float2bfloat16(a.y);
      u.h[2] = __float2bfloat16(a.z); u.h[3] = __float2bfloat16(a.w);
      u.h[4] = __float2bfloat16(b.x); u.h[5] = __float2bfloat16(b.y);
      u.h[6] = __float2bfloat16(b.z); u.h[7] = __float2bfloat16(b.w);
      *(int4*)(xb + idx) = u.v;
    }
    return;
  }

  // ---- build branch ----
  const int bx = bid & 15;
  const int by = bid >> 4;
  const int n0 = by * BWR;
  const int k0 = bx * BWC;

  {  // stage U: 32x32 floats
    const int idx = t * 4;
    const int row = idx >> 5, rr = idx & 31;
    float4 uv = *(const float4*)(U + (size_t)(n0 + row) * RANKd + rr);
    U_s[row][rr] = uv.x; U_s[row][rr + 1] = uv.y;
    U_s[row][rr + 2] = uv.z; U_s[row][rr + 3] = uv.w;
  }
  #pragma unroll
  for (int i = 0; i < 8; ++i) {  // stage V: 32x256 floats
    const int idx = i * 1024 + t * 4;
    const int vr = idx >> 8, vc = idx & 255;
    *(float4*)&V_s[vr][vc] = *(const float4*)(V + (size_t)vr * Kd + k0 + vc);
  }
  __syncthreads();

  const int rs = t >> 5;
  const int cs = t & 31;
  const int row0 = n0 + rs * 4;
  const int c0 = cs * 4;
  const int c1 = 128 + cs * 4;
  const int g0 = k0 >> 7, g1 = g0 + 1;

  float acc[4][8];
  #pragma unroll
  for (int j = 0; j < 4; ++j) {
    const int* qr = q + (size_t)(row0 + j) * Kd + k0;
    int4 a = *(const int4*)(qr + c0);
    int4 b = *(const int4*)(qr + c1);
    const float s0 = scales[(size_t)(row0 + j) * NG + g0];
    const float s1 = scales[(size_t)(row0 + j) * NG + g1];
    acc[j][0] = (float)(a.x - 8) * s0; acc[j][1] = (float)(a.y - 8) * s0;
    acc[j][2] = (float)(a.z - 8) * s0; acc[j][3] = (float)(a.w - 8) * s0;
    acc[j][4] = (float)(b.x - 8) * s1; acc[j][5] = (float)(b.y - 8) * s1;
    acc[j][6] = (float)(b.z - 8) * s1; acc[j][7] = (float)(b.w - 8) * s1;
  }

  #pragma unroll 4
  for (int r = 0; r < RANKd; ++r) {
    float4 v0 = *(const float4*)&V_s[r][c0];
    float4 v1 = *(const float4*)&V_s[r][c1];
    #pragma unroll
    for (int j = 0; j < 4; ++j) {
      const float u = U_s[rs * 4 + j][r];
      acc[j][0] += u * v0.x; acc[j][1] += u * v0.y;
      acc[j][2] += u * v0.z; acc[j][3] += u * v0.w;
      acc[j][4] += u * v1.x; acc[j][5] += u * v1.y;
      acc[j][6] += u * v1.z; acc[j][7] += u * v1.w;
    }
  }

  #pragma unroll
  for (int j = 0; j < 4; ++j) {
    union { __hip_bfloat16 h[4]; uint2 v; } o0, o1;
    o0.h[0] = __float2bfloat16(acc[j][0]); o0.h[1] = __float2bfloat16(acc[j][1]);
    o0.h[2] = __float2bfloat16(acc[j][2]); o0.h[3] = __float2bfloat16(acc[j][3]);
    o1.h[0] = __float2bfloat16(acc[j][4]); o1.h[1] = __float2bfloat16(acc[j][5]);
    o1.h[2] = __float2bfloat16(acc[j][6]); o1.h[3] = __float2bfloat16(acc[j][7]);
    __hip_bfloat16* wr = W + (size_t)(row0 + j) * Kd + k0;
    *(uint2*)(wr + c0) = o0.v;
    *(uint2*)(wr + c1) = o1.v;
  }
}

// ---------------------------------------------------------------------------
// gemm128: 128x256 tile, 4 waves (256 thr), 1Mx4N wave grid, 4x2 32x32x16
// MFMA frags/wave (same per-wave work as the 300us round-1 kernel).
//
// ROUND 3 THEORY (unchanged, resubmitted after acquisition timeout):
// occupancy was REGISTER-capped (232 unified regs/wave -> 2 waves/SIMD =
// 8 waves/CU), so 8-wave blocks pin to 1 block/CU and the barrier-locked
// phases serialize LDS (~1400cyc) with MFMA (~1033cyc). 4-wave blocks keep
// the same 8 waves/CU but as TWO independent blocks: one block's MFMA
// overlaps the other's LDS/barrier window (m114).
//
// Pipeline: 3 slots x 24 KB (A 8K + B 16K) = 72 KB/block; 2 blocks = 144 KB.
// Round-1-proven phase order: ds_read(slot g) -> issue half g+2 (6 gloads)
// -> vmcnt(6) [half g+1 landed; half g+2 stays in flight across barriers]
// -> barrier -> lgkmcnt(0) -> 16 MFMA -> barrier. Slot-overwrite safe:
// issue(g+2) targets slot (g-1)%3 whose readers all passed their lgkmcnt(0)
// before phase g-1's tail barrier. Chunk-XOR swizzle geometry unchanged:
// LDS chunk c of row r holds global chunk c ^ ((r>>1)&3); staging
// pre-swizzles the GLOBAL source chunk so gload_lds dest stays linear.
// ---------------------------------------------------------------------------
#define WAIT_VM6 asm volatile("s_waitcnt vmcnt(6)" ::: "memory")
#define WAIT_VM0 asm volatile("s_waitcnt vmcnt(0)" ::: "memory")
#define WAIT_NONE ((void)0)

// stage one K-half H into slot SLOT: A 8 KB (2 insts) + B 16 KB (4 insts)
#define ISSUE6(H, SLOT)                                                         \
  {                                                                             \
    char* sb_ = smc + (SLOT) * 24576;                                           \
    const size_t ko_ = (size_t)(H) * 32;                                        \
    __builtin_amdgcn_global_load_lds((GAS void*)(ag0 + ko_),                    \
        (LAS void*)(sb_ + ldsA), 16, 0, 0);                                     \
    __builtin_amdgcn_global_load_lds((GAS void*)(ag0 + 16 * Kd + ko_),          \
        (LAS void*)(sb_ + ldsA + 1024), 16, 0, 0);                              \
    __builtin_amdgcn_global_load_lds((GAS void*)(bg0 + ko_),                    \
        (LAS void*)(sb_ + ldsB), 16, 0, 0);                                     \
    __builtin_amdgcn_global_load_lds((GAS void*)(bg0 + 16 * Kd + ko_),          \
        (LAS void*)(sb_ + ldsB + 1024), 16, 0, 0);                              \
    __builtin_amdgcn_global_load_lds((GAS void*)(bg0 + 32 * Kd + ko_),          \
        (LAS void*)(sb_ + ldsB + 2048), 16, 0, 0);                              \
    __builtin_amdgcn_global_load_lds((GAS void*)(bg0 + 48 * Kd + ko_),          \
        (LAS void*)(sb_ + ldsB + 3072), 16, 0, 0);                              \
  }

// one phase: compute half G from slot SCUR, prefetch half G+2 into SNXT2
#define GPHASE(G, SCUR, SNXT2, WAITSTMT, DO_ISSUE)                              \
  {                                                                             \
    const char* as_ = (const char*)smc + (SCUR) * 24576;                        \
    bf16x8 af0[4], af1[4], bfA[2], bfB[2];                                      \
    _Pragma("unroll")                                                           \
    for (int mi = 0; mi < 4; ++mi) {                                            \
      af0[mi] = *(const bf16x8*)(as_ + aro + mi * 2048 + cq0);                  \
      af1[mi] = *(const bf16x8*)(as_ + aro + mi * 2048 + cq1);                  \
    }                                                                           \
    _Pragma("unroll")                                                           \
    for (int nj = 0; nj < 2; ++nj) {                                            \
      bfA[nj] = *(const bf16x8*)(as_ + bro + nj * 2048 + cq0);                  \
      bfB[nj] = *(const bf16x8*)(as_ + bro + nj * 2048 + cq1);                  \
    }                                                                           \
    __builtin_amdgcn_sched_barrier(0);                                          \
    if (DO_ISSUE) { ISSUE6((G) + 2, SNXT2); }                                   \
    __builtin_amdgcn_sched_barrier(0);                                          \
    WAITSTMT;                                                                   \
    __builtin_amdgcn_s_barrier();                                               \
    asm volatile("s_waitcnt lgkmcnt(0)" ::: "memory");                          \
    __builtin_amdgcn_sched_barrier(0);                                          \
    __builtin_amdgcn_s_setprio(1);                                              \
    _Pragma("unroll")                                                           \
    for (int mi = 0; mi < 4; ++mi)                                              \
      _Pragma("unroll")                                                         \
      for (int nj = 0; nj < 2; ++nj)                                            \
        acc[mi][nj] = __builtin_amdgcn_mfma_f32_32x32x16_bf16(                  \
            af0[mi], bfA[nj], acc[mi][nj], 0, 0, 0);                            \
    _Pragma("unroll")                                                           \
    for (int mi = 0; mi < 4; ++mi)                                              \
      _Pragma("unroll")                                                         \
      for (int nj = 0; nj < 2; ++nj)                                            \
        acc[mi][nj] = __builtin_amdgcn_mfma_f32_32x32x16_bf16(                  \
            af1[mi], bfB[nj], acc[mi][nj], 0, 0, 0);                            \
    __builtin_amdgcn_s_setprio(0);                                              \
    __builtin_amdgcn_s_barrier();                                               \
  }

__global__ __launch_bounds__(256, 2) void gemm128(
    const __hip_bfloat16* __restrict__ A, const __hip_bfloat16* __restrict__ Bt,
    const float* __restrict__ bias, float* __restrict__ C)
{
  // 3 slots x 24 KB; within a slot: A rows [0,128) at +0, B rows [0,256) at +8192.
  __shared__ __align__(16) char sm[73728];
  char* const smc = sm;

  int bx, by;
  {
    const int bid = blockIdx.x;
    if (gridDim.x == 1024) {
      // XCD-aware (8 XCDs, 128 blocks each). Within an XCD walk column-major:
      // 8 consecutive blocks share one 2 MB B-panel (L2-resident).
      const int x = bid & 7, loc = bid >> 3;       // loc in [0,128)
      by = x * 8 + (loc & 7);                      // 8 tile-rows per XCD
      bx = loc >> 3;                               // 16 tile-cols
    } else {
      by = bid >> 4;
      bx = bid & 15;
    }
  }
  const int bm0 = by * 128, bn0 = bx * 256;

  const int t = threadIdx.x;
  const int l = t & 63, w = t >> 6;                // 4 waves

  // ---- staging addressing: wave w stages A rows [w*32,w*32+32),
  //      B rows [w*64, w*64+64); lane l -> row sr=l>>2 within 16-row window,
  //      pre-swizzled global chunk schk = (l&3) ^ ((l>>3)&3) = (l&3)^((row>>1)&3)
  const int sr   = l >> 2;
  const int schk = (l & 3) ^ ((l >> 3) & 3);
  const __hip_bfloat16* ag0 = A  + (size_t)(bm0 + w * 32 + sr) * Kd + schk * 8;
  const __hip_bfloat16* bg0 = Bt + (size_t)(bn0 + w * 64 + sr) * Kd + schk * 8;
  const int ldsA = w * 2048 + l * 16;
  const int ldsB = 8192 + w * 4096 + l * 16;

  // ---- fragment addressing: wave w owns output cols [w*64, w*64+64);
  //      all waves share the 128-row A panel.
  const int rl = l & 31, kh = l >> 5, swz = (rl >> 1) & 3;
  const int aro = rl * 64;
  const int bro = 8192 + (w * 64 + rl) * 64;
  const int cq0 = (kh ^ swz) * 16;                 // ks=0 chunk slot
  const int cq1 = ((2 + kh) ^ swz) * 16;           // ks=1 chunk slot

  f32x16 acc[4][2];
  #pragma unroll
  for (int mi = 0; mi < 4; ++mi)
    #pragma unroll
    for (int nj = 0; nj < 2; ++nj)
      acc[mi][nj] = (f32x16)(0.f);

  // ---- prologue: fill slots 0,1 (halves 0,1); half 0 must be landed.
  ISSUE6(0, 0);
  ISSUE6(1, 1);
  WAIT_VM6;
  __builtin_amdgcn_s_barrier();
  __builtin_amdgcn_sched_barrier(0);

  // ---- 128 phases. Steady state: 12 loads (2 halves) in flight, vmcnt(6).
  for (int g = 0; g < 126; g += 3) {
    GPHASE(g,     0, 2, WAIT_VM6, 1);
    GPHASE(g + 1, 1, 0, WAIT_VM6, 1);
    GPHASE(g + 2, 2, 1, WAIT_VM6, 1);
  }
  GPHASE(126, 0, 2, WAIT_VM0, 0);
  GPHASE(127, 1, 0, WAIT_NONE, 0);

  // ---- epilogue: C/D layout col=lane&31, row=(reg&3)+8*(reg>>2)+4*(lane>>5)
  #pragma unroll
  for (int nj = 0; nj < 2; ++nj) {
    const int col = bn0 + w * 64 + nj * 32 + rl;
    const float bz = bias[col];
    #pragma unroll
    for (int mi = 0; mi < 4; ++mi) {
      const int rbase = bm0 + mi * 32 + 4 * kh;
      #pragma unroll
      for (int reg = 0; reg < 16; ++reg) {
        const int row = rbase + (reg & 3) + 8 * (reg >> 2);
        C[(size_t)row * Nd + col] = acc[mi][nj][reg] + bz;
      }
    }
  }
}

#undef GPHASE
#undef ISSUE6

// ---------------------------------------------------------------------------
// gemm_bt: old 128x128 kernel, kept only as the small-workspace fallback
// (fp32-A path).
// ---------------------------------------------------------------------------
template <bool ABF16>
__global__ __launch_bounds__(256) void gemm_bt(
    const void* __restrict__ Ap, const __hip_bfloat16* __restrict__ Bt,
    const float* __restrict__ bias, float* __restrict__ C)
{
  __shared__ __hip_bfloat16 As[BM * BK];   // 16 KB = 2 slabs x 8 KB
  __shared__ __hip_bfloat16 Bs[BN * BK];   // 16 KB

  const int t  = threadIdx.x;
  const int l  = t & 63;
  const int w  = t >> 6;
  const int wm = w >> 1;
  const int wn = w & 1;
  const int bm0 = blockIdx.y * BM;
  const int bn0 = blockIdx.x * BN;

  f32x16 acc[2][2];
  #pragma unroll
  for (int i = 0; i < 2; ++i)
    #pragma unroll
    for (int j = 0; j < 2; ++j)
      acc[i][j] = (f32x16)(0.f);

  const __hip_bfloat16* Abf = (const __hip_bfloat16*)Ap;
  const float*          A32 = (const float*)Ap;

  const int sr   = l >> 2;
  const int schk = (l & 3) ^ ((l >> 3) & 3);
  const __hip_bfloat16* ag0 = Abf + (size_t)(bm0 + w * 32 + sr) * Kd + schk * 8;
  const __hip_bfloat16* bg0 = Bt  + (size_t)(bn0 + w * 32 + sr) * Kd + schk * 8;
  char* asb = (char*)As + w * 2048;
  char* bsb = (char*)Bs + w * 2048;

  const int rl = l & 31, kh = l >> 5, swz = (rl >> 1) & 3;
  const char* Ard = (const char*)As + (wm * 64 + rl) * 64;
  const char* Brd = (const char*)Bs + (wn * 64 + rl) * 64;

  const int arow = t >> 1, aslab = t & 1, arx = (arow >> 1) & 3;
  const float* a32p = A32 + (size_t)(bm0 + arow) * Kd + aslab * 32;
  char* awr = (char*)As + aslab * 8192 + arow * 64;

  for (int kt = 0; kt < Kd / BK; ++kt) {
    if constexpr (ABF16) {
      const __hip_bfloat16* ag = ag0 + kt * BK;
      __builtin_amdgcn_global_load_lds((GAS void*)ag,               (LAS void*)asb,                16, 0, 0);
      __builtin_amdgcn_global_load_lds((GAS void*)(ag + 16 * Kd),   (LAS void*)(asb + 1024),       16, 0, 0);
      __builtin_amdgcn_global_load_lds((GAS void*)(ag + 32),        (LAS void*)(asb + 8192),       16, 0, 0);
      __builtin_amdgcn_global_load_lds((GAS void*)(ag + 16*Kd + 32),(LAS void*)(asb + 8192 + 1024),16, 0, 0);
    } else {
      const float* ap = a32p + kt * BK;
      #pragma unroll
      for (int cc = 0; cc < 4; ++cc) {
        float4 f0 = ((const float4*)ap)[cc * 2];
        float4 f1 = ((const float4*)ap)[cc * 2 + 1];
        union { __hip_bfloat16 h[8]; int4 v; } u;
        u.h[0] = __float2bfloat16(f0.x); u.h[1] = __float2bfloat16(f0.y);
        u.h[2] = __float2bfloat16(f0.z); u.h[3] = __float2bfloat16(f0.w);
        u.h[4] = __float2bfloat16(f1.x); u.h[5] = __float2bfloat16(f1.y);
        u.h[6] = __float2bfloat16(f1.z); u.h[7] = __float2bfloat16(f1.w);
        *(int4*)(awr + ((cc ^ arx) * 16)) = u.v;
      }
    }
    {
      const __hip_bfloat16* bg = bg0 + kt * BK;
      __builtin_amdgcn_global_load_lds((GAS void*)bg,               (LAS void*)bsb,                16, 0, 0);
      __builtin_amdgcn_global_load_lds((GAS void*)(bg + 16 * Kd),   (LAS void*)(bsb + 1024),       16, 0, 0);
      __builtin_amdgcn_global_load_lds((GAS void*)(bg + 32),        (LAS void*)(bsb + 8192),       16, 0, 0);
      __builtin_amdgcn_global_load_lds((GAS void*)(bg + 16*Kd + 32),(LAS void*)(bsb + 8192 + 1024),16, 0, 0);
    }

    __syncthreads();

    bf16x8 af[2][4], bfr[2][4];
    #pragma unroll
    for (int mi = 0; mi < 2; ++mi)
      #pragma unroll
      for (int ks = 0; ks < 4; ++ks)
        af[mi][ks] = *(const bf16x8*)(Ard + (ks >> 1) * 8192 + mi * 2048 +
                                      ((((ks & 1) * 2 + kh) ^ swz) * 16));
    #pragma unroll
    for (int nj = 0; nj < 2; ++nj)
      #pragma unroll
      for (int ks = 0; ks < 4; ++ks)
        bfr[nj][ks] = *(const bf16x8*)(Brd + (ks >> 1) * 8192 + nj * 2048 +
                                       ((((ks & 1) * 2 + kh) ^ swz) * 16));

    #pragma unroll
    for (int ks = 0; ks < 4; ++ks)
      #pragma unroll
      for (int mi = 0; mi < 2; ++mi)
        #pragma unroll
        for (int nj = 0; nj < 2; ++nj)
          acc[mi][nj] = __builtin_amdgcn_mfma_f32_32x32x16_bf16(
              af[mi][ks], bfr[nj][ks], acc[mi][nj], 0, 0, 0);

    __syncthreads();
  }

  #pragma unroll
  for (int nj = 0; nj < 2; ++nj) {
    const int col = bn0 + wn * 64 + nj * 32 + rl;
    const float bz = bias[col];
    #pragma unroll
    for (int mi = 0; mi < 2; ++mi) {
      const int rbase = bm0 + wm * 64 + mi * 32 + 4 * kh;
      #pragma unroll
      for (int reg = 0; reg < 16; ++reg) {
        const int row = rbase + (reg & 3) + 8 * (reg >> 2);
        C[(size_t)row * Nd + col] = acc[mi][nj][reg] + bz;
      }
    }
  }
}

// ---------------------------------------------------------------------------
extern "C" void kernel_launch(void* const* d_in, const int* in_sizes, int n_in,
                              void* d_out, int out_size, void* d_ws, size_t ws_size,
                              hipStream_t stream)
{
  const float* x      = (const float*)d_in[0];
  const int*   q      = (const int*)  d_in[1];
  const float* scales = (const float*)d_in[2];
  const float* U      = (const float*)d_in[3];
  const float* V      = (const float*)d_in[4];
  const float* bias   = (const float*)d_in[5];
  float* out = (float*)d_out;

  const int M = in_sizes[0] / Kd;   // B*S = 8192

  __hip_bfloat16* Wb = (__hip_bfloat16*)d_ws;
  const size_t wbytes = (size_t)Nd * Kd * sizeof(__hip_bfloat16);
  const size_t xbytes = (size_t)M  * Kd * sizeof(__hip_bfloat16);

  if (ws_size >= wbytes + xbytes && (M % 128) == 0) {
    __hip_bfloat16* Xb = (__hip_bfloat16*)((char*)d_ws + wbytes);
    const int nconv = (int)(((size_t)M * Kd) / 8192);
    prep<<<dim3(NBUILD + nconv), dim3(256), 0, stream>>>(q, scales, U, V, Wb, x, Xb);
    const int nblk = (M / 128) * (Nd / 256);
    gemm128<<<dim3(nblk), dim3(256), 0, stream>>>(Xb, Wb, bias, out);
  } else {
    prep<<<dim3(NBUILD), dim3(256), 0, stream>>>(q, scales, U, V, Wb, x, nullptr);
    dim3 grid(Nd / BN, M / BM);
    gemm_bt<false><<<grid, dim3(256), 0, stream>>>((const void*)x, Wb, bias, out);
  }
}

// Round 5
// 549.063 us; speedup vs baseline: 1.1123x; 1.0052x over previous
//
#include <hip/hip_runtime.h>
#include <hip/hip_bf16.h>

#define GAS __attribute__((address_space(1)))
#define LAS __attribute__((address_space(3)))

typedef __bf16 bf16x8 __attribute__((ext_vector_type(8)));
typedef float f32x16 __attribute__((ext_vector_type(16)));

constexpr int Kd = 4096;   // IN
constexpr int Nd = 4096;   // OUT
constexpr int RANKd = 32;
constexpr int NG = 32;     // scale groups
constexpr int BM = 128, BN = 128, BK = 64;

// ---------------------------------------------------------------------------
// prep: fused W-build + x fp32->bf16 convert (unchanged).
// ---------------------------------------------------------------------------
constexpr int BWR = 32, BWC = 256;
constexpr int NBUILD = (Nd / BWR) * (Kd / BWC);   // 2048

__global__ __launch_bounds__(256) void prep(
    const int* __restrict__ q, const float* __restrict__ scales,
    const float* __restrict__ U, const float* __restrict__ V,
    __hip_bfloat16* __restrict__ W,
    const float* __restrict__ x, __hip_bfloat16* __restrict__ xb)
{
  __shared__ float V_s[RANKd][BWC + 4];
  __shared__ float U_s[BWR][RANKd + 1];

  const int t = threadIdx.x;
  const int bid = blockIdx.x;

  if (bid >= NBUILD) {   // ---- convert branch ----
    const size_t base = (size_t)(bid - NBUILD) * 8192;
    #pragma unroll
    for (int i = 0; i < 4; ++i) {
      const size_t idx = base + i * 2048 + t * 8;
      float4 a = *(const float4*)(x + idx);
      float4 b = *(const float4*)(x + idx + 4);
      union { __hip_bfloat16 h[8]; int4 v; } u;
      u.h[0] = __float2bfloat16(a.x); u.h[1] = __float2bfloat16(a.y);
      u.h[2] = __float2bfloat16(a.z); u.h[3] = __float2bfloat16(a.w);
      u.h[4] = __float2bfloat16(b.x); u.h[5] = __float2bfloat16(b.y);
      u.h[6] = __float2bfloat16(b.z); u.h[7] = __float2bfloat16(b.w);
      *(int4*)(xb + idx) = u.v;
    }
    return;
  }

  // ---- build branch ----
  const int bx = bid & 15;
  const int by = bid >> 4;
  const int n0 = by * BWR;
  const int k0 = bx * BWC;

  {  // stage U: 32x32 floats
    const int idx = t * 4;
    const int row = idx >> 5, rr = idx & 31;
    float4 uv = *(const float4*)(U + (size_t)(n0 + row) * RANKd + rr);
    U_s[row][rr] = uv.x; U_s[row][rr + 1] = uv.y;
    U_s[row][rr + 2] = uv.z; U_s[row][rr + 3] = uv.w;
  }
  #pragma unroll
  for (int i = 0; i < 8; ++i) {  // stage V: 32x256 floats
    const int idx = i * 1024 + t * 4;
    const int vr = idx >> 8, vc = idx & 255;
    *(float4*)&V_s[vr][vc] = *(const float4*)(V + (size_t)vr * Kd + k0 + vc);
  }
  __syncthreads();

  const int rs = t >> 5;
  const int cs = t & 31;
  const int row0 = n0 + rs * 4;
  const int c0 = cs * 4;
  const int c1 = 128 + cs * 4;
  const int g0 = k0 >> 7, g1 = g0 + 1;

  float acc[4][8];
  #pragma unroll
  for (int j = 0; j < 4; ++j) {
    const int* qr = q + (size_t)(row0 + j) * Kd + k0;
    int4 a = *(const int4*)(qr + c0);
    int4 b = *(const int4*)(qr + c1);
    const float s0 = scales[(size_t)(row0 + j) * NG + g0];
    const float s1 = scales[(size_t)(row0 + j) * NG + g1];
    acc[j][0] = (float)(a.x - 8) * s0; acc[j][1] = (float)(a.y - 8) * s0;
    acc[j][2] = (float)(a.z - 8) * s0; acc[j][3] = (float)(a.w - 8) * s0;
    acc[j][4] = (float)(b.x - 8) * s1; acc[j][5] = (float)(b.y - 8) * s1;
    acc[j][6] = (float)(b.z - 8) * s1; acc[j][7] = (float)(b.w - 8) * s1;
  }

  #pragma unroll 4
  for (int r = 0; r < RANKd; ++r) {
    float4 v0 = *(const float4*)&V_s[r][c0];
    float4 v1 = *(const float4*)&V_s[r][c1];
    #pragma unroll
    for (int j = 0; j < 4; ++j) {
      const float u = U_s[rs * 4 + j][r];
      acc[j][0] += u * v0.x; acc[j][1] += u * v0.y;
      acc[j][2] += u * v0.z; acc[j][3] += u * v0.w;
      acc[j][4] += u * v1.x; acc[j][5] += u * v1.y;
      acc[j][6] += u * v1.z; acc[j][7] += u * v1.w;
    }
  }

  #pragma unroll
  for (int j = 0; j < 4; ++j) {
    union { __hip_bfloat16 h[4]; uint2 v; } o0, o1;
    o0.h[0] = __float2bfloat16(acc[j][0]); o0.h[1] = __float2bfloat16(acc[j][1]);
    o0.h[2] = __float2bfloat16(acc[j][2]); o0.h[3] = __float2bfloat16(acc[j][3]);
    o1.h[0] = __float2bfloat16(acc[j][4]); o1.h[1] = __float2bfloat16(acc[j][5]);
    o1.h[2] = __float2bfloat16(acc[j][6]); o1.h[3] = __float2bfloat16(acc[j][7]);
    __hip_bfloat16* wr = W + (size_t)(row0 + j) * Kd + k0;
    *(uint2*)(wr + c0) = o0.v;
    *(uint2*)(wr + c1) = o1.v;
  }
}

// ---------------------------------------------------------------------------
// gemm128: 128x256 tile, 4 waves (256 thr), 3-slot pipeline — round-3/4
// structure, ROUND 5 CHANGE: split-drain counted lgkmcnt.
//
// Round-4 PMC post-mortem: per-CU phase = ~2800 cyc = ds-read drain (~1150)
// + MFMA (~1033) + DMA (~400) + sync (~200), SERIALIZED: the full-drain
// lgkmcnt(0) after the barrier makes every wave wait for ALL 12 reads
// before ANY MFMA — LDS port and MFMA pipe alternate instead of overlap
// (identical 2800 cyc in 8-wave/1-block and 4-wave/2-block variants).
//
// Fix: issue reads in two FIFO groups (ks0: af0 x4 + bfA x2; ks1: af1 x4 +
// bfB x2), then lgkmcnt(6) -> 8 MFMA (ks0) -> lgkmcnt(0) -> 8 MFMA (ks1).
// ks1's read drain overlaps ks0's MFMA cluster. sched_barrier(0) fences
// after each counted waitcnt (rule #18: MFMA hoists past asm-lgkmcnt) and
// between read groups (pin FIFO order for the count).
//
// Hazard analysis unchanged from round 3: all 12 reads of phase g still
// complete before phase g's tail barrier (lgkmcnt(0) precedes the ks1 MFMA
// cluster); ISSUE(g+2) -> slot (g-1)%3 happens after that barrier, so no
// wave can overwrite a slot with pending readers. vmcnt(6) steady state
// keeps 2 halves in flight. Chunk-XOR swizzle geometry unchanged.
// ---------------------------------------------------------------------------
#define WAIT_VM6 asm volatile("s_waitcnt vmcnt(6)" ::: "memory")
#define WAIT_VM0 asm volatile("s_waitcnt vmcnt(0)" ::: "memory")
#define WAIT_NONE ((void)0)

// stage one K-half H into slot SLOT: A 8 KB (2 insts) + B 16 KB (4 insts)
#define ISSUE6(H, SLOT)                                                         \
  {                                                                             \
    char* sb_ = smc + (SLOT) * 24576;                                           \
    const size_t ko_ = (size_t)(H) * 32;                                        \
    __builtin_amdgcn_global_load_lds((GAS void*)(ag0 + ko_),                    \
        (LAS void*)(sb_ + ldsA), 16, 0, 0);                                     \
    __builtin_amdgcn_global_load_lds((GAS void*)(ag0 + 16 * Kd + ko_),          \
        (LAS void*)(sb_ + ldsA + 1024), 16, 0, 0);                              \
    __builtin_amdgcn_global_load_lds((GAS void*)(bg0 + ko_),                    \
        (LAS void*)(sb_ + ldsB), 16, 0, 0);                                     \
    __builtin_amdgcn_global_load_lds((GAS void*)(bg0 + 16 * Kd + ko_),          \
        (LAS void*)(sb_ + ldsB + 1024), 16, 0, 0);                              \
    __builtin_amdgcn_global_load_lds((GAS void*)(bg0 + 32 * Kd + ko_),          \
        (LAS void*)(sb_ + ldsB + 2048), 16, 0, 0);                              \
    __builtin_amdgcn_global_load_lds((GAS void*)(bg0 + 48 * Kd + ko_),          \
        (LAS void*)(sb_ + ldsB + 3072), 16, 0, 0);                              \
  }

// one phase: compute half G from slot SCUR, prefetch half G+2 into SNXT2.
// Split-drain: lgkmcnt(6) gates ks0 MFMA; ks1 reads drain under them.
#define GPHASE(G, SCUR, SNXT2, WAITSTMT, DO_ISSUE)                              \
  {                                                                             \
    const char* as_ = (const char*)smc + (SCUR) * 24576;                        \
    bf16x8 af0[4], af1[4], bfA[2], bfB[2];                                      \
    _Pragma("unroll")                                                           \
    for (int mi = 0; mi < 4; ++mi)                                              \
      af0[mi] = *(const bf16x8*)(as_ + aro + mi * 2048 + cq0);                  \
    _Pragma("unroll")                                                           \
    for (int nj = 0; nj < 2; ++nj)                                              \
      bfA[nj] = *(const bf16x8*)(as_ + bro + nj * 2048 + cq0);                  \
    __builtin_amdgcn_sched_barrier(0);  /* pin FIFO: ks0 group issued first */  \
    _Pragma("unroll")                                                           \
    for (int mi = 0; mi < 4; ++mi)                                              \
      af1[mi] = *(const bf16x8*)(as_ + aro + mi * 2048 + cq1);                  \
    _Pragma("unroll")                                                           \
    for (int nj = 0; nj < 2; ++nj)                                              \
      bfB[nj] = *(const bf16x8*)(as_ + bro + nj * 2048 + cq1);                  \
    __builtin_amdgcn_sched_barrier(0);                                          \
    if (DO_ISSUE) { ISSUE6((G) + 2, SNXT2); }                                   \
    __builtin_amdgcn_sched_barrier(0);                                          \
    WAITSTMT;                                                                   \
    __builtin_amdgcn_s_barrier();                                               \
    asm volatile("s_waitcnt lgkmcnt(6)" ::: "memory");                          \
    __builtin_amdgcn_sched_barrier(0);                                          \
    __builtin_amdgcn_s_setprio(1);                                              \
    _Pragma("unroll")                                                           \
    for (int mi = 0; mi < 4; ++mi)                                              \
      _Pragma("unroll")                                                         \
      for (int nj = 0; nj < 2; ++nj)                                            \
        acc[mi][nj] = __builtin_amdgcn_mfma_f32_32x32x16_bf16(                  \
            af0[mi], bfA[nj], acc[mi][nj], 0, 0, 0);                            \
    __builtin_amdgcn_sched_barrier(0);                                          \
    asm volatile("s_waitcnt lgkmcnt(0)" ::: "memory");                          \
    __builtin_amdgcn_sched_barrier(0);                                          \
    _Pragma("unroll")                                                           \
    for (int mi = 0; mi < 4; ++mi)                                              \
      _Pragma("unroll")                                                         \
      for (int nj = 0; nj < 2; ++nj)                                            \
        acc[mi][nj] = __builtin_amdgcn_mfma_f32_32x32x16_bf16(                  \
            af1[mi], bfB[nj], acc[mi][nj], 0, 0, 0);                            \
    __builtin_amdgcn_s_setprio(0);                                              \
    __builtin_amdgcn_s_barrier();                                               \
  }

__global__ __launch_bounds__(256, 2) void gemm128(
    const __hip_bfloat16* __restrict__ A, const __hip_bfloat16* __restrict__ Bt,
    const float* __restrict__ bias, float* __restrict__ C)
{
  // 3 slots x 24 KB; within a slot: A rows [0,128) at +0, B rows [0,256) at +8192.
  __shared__ __align__(16) char sm[73728];
  char* const smc = sm;

  int bx, by;
  {
    const int bid = blockIdx.x;
    if (gridDim.x == 1024) {
      // XCD-aware (8 XCDs, 128 blocks each). Within an XCD walk column-major:
      // 8 consecutive blocks share one 2 MB B-panel (L2-resident).
      const int x = bid & 7, loc = bid >> 3;       // loc in [0,128)
      by = x * 8 + (loc & 7);                      // 8 tile-rows per XCD
      bx = loc >> 3;                               // 16 tile-cols
    } else {
      by = bid >> 4;
      bx = bid & 15;
    }
  }
  const int bm0 = by * 128, bn0 = bx * 256;

  const int t = threadIdx.x;
  const int l = t & 63, w = t >> 6;                // 4 waves

  // ---- staging addressing: wave w stages A rows [w*32,w*32+32),
  //      B rows [w*64, w*64+64); lane l -> row sr=l>>2 within 16-row window,
  //      pre-swizzled global chunk schk = (l&3) ^ ((l>>3)&3) = (l&3)^((row>>1)&3)
  const int sr   = l >> 2;
  const int schk = (l & 3) ^ ((l >> 3) & 3);
  const __hip_bfloat16* ag0 = A  + (size_t)(bm0 + w * 32 + sr) * Kd + schk * 8;
  const __hip_bfloat16* bg0 = Bt + (size_t)(bn0 + w * 64 + sr) * Kd + schk * 8;
  const int ldsA = w * 2048 + l * 16;
  const int ldsB = 8192 + w * 4096 + l * 16;

  // ---- fragment addressing: wave w owns output cols [w*64, w*64+64);
  //      all waves share the 128-row A panel.
  const int rl = l & 31, kh = l >> 5, swz = (rl >> 1) & 3;
  const int aro = rl * 64;
  const int bro = 8192 + (w * 64 + rl) * 64;
  const int cq0 = (kh ^ swz) * 16;                 // ks=0 chunk slot
  const int cq1 = ((2 + kh) ^ swz) * 16;           // ks=1 chunk slot

  f32x16 acc[4][2];
  #pragma unroll
  for (int mi = 0; mi < 4; ++mi)
    #pragma unroll
    for (int nj = 0; nj < 2; ++nj)
      acc[mi][nj] = (f32x16)(0.f);

  // ---- prologue: fill slots 0,1 (halves 0,1); half 0 must be landed.
  ISSUE6(0, 0);
  ISSUE6(1, 1);
  WAIT_VM6;
  __builtin_amdgcn_s_barrier();
  __builtin_amdgcn_sched_barrier(0);

  // ---- 128 phases. Steady state: 12 loads (2 halves) in flight, vmcnt(6).
  for (int g = 0; g < 126; g += 3) {
    GPHASE(g,     0, 2, WAIT_VM6, 1);
    GPHASE(g + 1, 1, 0, WAIT_VM6, 1);
    GPHASE(g + 2, 2, 1, WAIT_VM6, 1);
  }
  GPHASE(126, 0, 2, WAIT_VM0, 0);
  GPHASE(127, 1, 0, WAIT_NONE, 0);

  // ---- epilogue: C/D layout col=lane&31, row=(reg&3)+8*(reg>>2)+4*(lane>>5)
  #pragma unroll
  for (int nj = 0; nj < 2; ++nj) {
    const int col = bn0 + w * 64 + nj * 32 + rl;
    const float bz = bias[col];
    #pragma unroll
    for (int mi = 0; mi < 4; ++mi) {
      const int rbase = bm0 + mi * 32 + 4 * kh;
      #pragma unroll
      for (int reg = 0; reg < 16; ++reg) {
        const int row = rbase + (reg & 3) + 8 * (reg >> 2);
        C[(size_t)row * Nd + col] = acc[mi][nj][reg] + bz;
      }
    }
  }
}

#undef GPHASE
#undef ISSUE6

// ---------------------------------------------------------------------------
// gemm_bt: old 128x128 kernel, kept only as the small-workspace fallback
// (fp32-A path).
// ---------------------------------------------------------------------------
template <bool ABF16>
__global__ __launch_bounds__(256) void gemm_bt(
    const void* __restrict__ Ap, const __hip_bfloat16* __restrict__ Bt,
    const float* __restrict__ bias, float* __restrict__ C)
{
  __shared__ __hip_bfloat16 As[BM * BK];   // 16 KB = 2 slabs x 8 KB
  __shared__ __hip_bfloat16 Bs[BN * BK];   // 16 KB

  const int t  = threadIdx.x;
  const int l  = t & 63;
  const int w  = t >> 6;
  const int wm = w >> 1;
  const int wn = w & 1;
  const int bm0 = blockIdx.y * BM;
  const int bn0 = blockIdx.x * BN;

  f32x16 acc[2][2];
  #pragma unroll
  for (int i = 0; i < 2; ++i)
    #pragma unroll
    for (int j = 0; j < 2; ++j)
      acc[i][j] = (f32x16)(0.f);

  const __hip_bfloat16* Abf = (const __hip_bfloat16*)Ap;
  const float*          A32 = (const float*)Ap;

  const int sr   = l >> 2;
  const int schk = (l & 3) ^ ((l >> 3) & 3);
  const __hip_bfloat16* ag0 = Abf + (size_t)(bm0 + w * 32 + sr) * Kd + schk * 8;
  const __hip_bfloat16* bg0 = Bt  + (size_t)(bn0 + w * 32 + sr) * Kd + schk * 8;
  char* asb = (char*)As + w * 2048;
  char* bsb = (char*)Bs + w * 2048;

  const int rl = l & 31, kh = l >> 5, swz = (rl >> 1) & 3;
  const char* Ard = (const char*)As + (wm * 64 + rl) * 64;
  const char* Brd = (const char*)Bs + (wn * 64 + rl) * 64;

  const int arow = t >> 1, aslab = t & 1, arx = (arow >> 1) & 3;
  const float* a32p = A32 + (size_t)(bm0 + arow) * Kd + aslab * 32;
  char* awr = (char*)As + aslab * 8192 + arow * 64;

  for (int kt = 0; kt < Kd / BK; ++kt) {
    if constexpr (ABF16) {
      const __hip_bfloat16* ag = ag0 + kt * BK;
      __builtin_amdgcn_global_load_lds((GAS void*)ag,               (LAS void*)asb,                16, 0, 0);
      __builtin_amdgcn_global_load_lds((GAS void*)(ag + 16 * Kd),   (LAS void*)(asb + 1024),       16, 0, 0);
      __builtin_amdgcn_global_load_lds((GAS void*)(ag + 32),        (LAS void*)(asb + 8192),       16, 0, 0);
      __builtin_amdgcn_global_load_lds((GAS void*)(ag + 16*Kd + 32),(LAS void*)(asb + 8192 + 1024),16, 0, 0);
    } else {
      const float* ap = a32p + kt * BK;
      #pragma unroll
      for (int cc = 0; cc < 4; ++cc) {
        float4 f0 = ((const float4*)ap)[cc * 2];
        float4 f1 = ((const float4*)ap)[cc * 2 + 1];
        union { __hip_bfloat16 h[8]; int4 v; } u;
        u.h[0] = __float2bfloat16(f0.x); u.h[1] = __float2bfloat16(f0.y);
        u.h[2] = __float2bfloat16(f0.z); u.h[3] = __float2bfloat16(f0.w);
        u.h[4] = __float2bfloat16(f1.x); u.h[5] = __float2bfloat16(f1.y);
        u.h[6] = __float2bfloat16(f1.z); u.h[7] = __float2bfloat16(f1.w);
        *(int4*)(awr + ((cc ^ arx) * 16)) = u.v;
      }
    }
    {
      const __hip_bfloat16* bg = bg0 + kt * BK;
      __builtin_amdgcn_global_load_lds((GAS void*)bg,               (LAS void*)bsb,                16, 0, 0);
      __builtin_amdgcn_global_load_lds((GAS void*)(bg + 16 * Kd),   (LAS void*)(bsb + 1024),       16, 0, 0);
      __builtin_amdgcn_global_load_lds((GAS void*)(bg + 32),        (LAS void*)(bsb + 8192),       16, 0, 0);
      __builtin_amdgcn_global_load_lds((GAS void*)(bg + 16*Kd + 32),(LAS void*)(bsb + 8192 + 1024),16, 0, 0);
    }

    __syncthreads();

    bf16x8 af[2][4], bfr[2][4];
    #pragma unroll
    for (int mi = 0; mi < 2; ++mi)
      #pragma unroll
      for (int ks = 0; ks < 4; ++ks)
        af[mi][ks] = *(const bf16x8*)(Ard + (ks >> 1) * 8192 + mi * 2048 +
                                      ((((ks & 1) * 2 + kh) ^ swz) * 16));
    #pragma unroll
    for (int nj = 0; nj < 2; ++nj)
      #pragma unroll
      for (int ks = 0; ks < 4; ++ks)
        bfr[nj][ks] = *(const bf16x8*)(Brd + (ks >> 1) * 8192 + nj * 2048 +
                                       ((((ks & 1) * 2 + kh) ^ swz) * 16));

    #pragma unroll
    for (int ks = 0; ks < 4; ++ks)
      #pragma unroll
      for (int mi = 0; mi < 2; ++mi)
        #pragma unroll
        for (int nj = 0; nj < 2; ++nj)
          acc[mi][nj] = __builtin_amdgcn_mfma_f32_32x32x16_bf16(
              af[mi][ks], bfr[nj][ks], acc[mi][nj], 0, 0, 0);

    __syncthreads();
  }

  #pragma unroll
  for (int nj = 0; nj < 2; ++nj) {
    const int col = bn0 + wn * 64 + nj * 32 + rl;
    const float bz = bias[col];
    #pragma unroll
    for (int mi = 0; mi < 2; ++mi) {
      const int rbase = bm0 + wm * 64 + mi * 32 + 4 * kh;
      #pragma unroll
      for (int reg = 0; reg < 16; ++reg) {
        const int row = rbase + (reg & 3) + 8 * (reg >> 2);
        C[(size_t)row * Nd + col] = acc[mi][nj][reg] + bz;
      }
    }
  }
}

// ---------------------------------------------------------------------------
extern "C" void kernel_launch(void* const* d_in, const int* in_sizes, int n_in,
                              void* d_out, int out_size, void* d_ws, size_t ws_size,
                              hipStream_t stream)
{
  const float* x      = (const float*)d_in[0];
  const int*   q      = (const int*)  d_in[1];
  const float* scales = (const float*)d_in[2];
  const float* U      = (const float*)d_in[3];
  const float* V      = (const float*)d_in[4];
  const float* bias   = (const float*)d_in[5];
  float* out = (float*)d_out;

  const int M = in_sizes[0] / Kd;   // B*S = 8192

  __hip_bfloat16* Wb = (__hip_bfloat16*)d_ws;
  const size_t wbytes = (size_t)Nd * Kd * sizeof(__hip_bfloat16);
  const size_t xbytes = (size_t)M  * Kd * sizeof(__hip_bfloat16);

  if (ws_size >= wbytes + xbytes && (M % 128) == 0) {
    __hip_bfloat16* Xb = (__hip_bfloat16*)((char*)d_ws + wbytes);
    const int nconv = (int)(((size_t)M * Kd) / 8192);
    prep<<<dim3(NBUILD + nconv), dim3(256), 0, stream>>>(q, scales, U, V, Wb, x, Xb);
    const int nblk = (M / 128) * (Nd / 256);
    gemm128<<<dim3(nblk), dim3(256), 0, stream>>>(Xb, Wb, bias, out);
  } else {
    prep<<<dim3(NBUILD), dim3(256), 0, stream>>>(q, scales, U, V, Wb, x, nullptr);
    dim3 grid(Nd / BN, M / BM);
    gemm_bt<false><<<grid, dim3(256), 0, stream>>>((const void*)x, Wb, bias, out);
  }
}